// Round 1
// baseline (548.358 us; speedup 1.0000x reference)
//
#include <hip/hip_runtime.h>
#include <math.h>

#define D 128
#define NB 16
#define LSTR 20          // LDS row stride (floats): 20*4=80 B keeps float4 16B-aligned, breaks pow2 bank stride
#define LN_EPS 1e-5f

// ---------------- transpose W_l, W_r (row-major [j][k] -> [k][j]) ----------------
__global__ void transpose_w(const float* __restrict__ Wl, const float* __restrict__ Wr,
                            float* __restrict__ WlT, float* __restrict__ WrT) {
    int t = blockIdx.x * blockDim.x + threadIdx.x;   // t = k*128 + j
    if (t < D * D) {
        int j = t & (D - 1);
        int k = t >> 7;
        WlT[k * D + j] = Wl[j * D + k];
        WrT[k * D + j] = Wr[j * D + k];
    }
}

// ---------------- histogram of dst ----------------
__global__ void hist_kernel(const int* __restrict__ dst, int* __restrict__ cnt, int E) {
    int e = blockIdx.x * blockDim.x + threadIdx.x;
    if (e < E) atomicAdd(&cnt[dst[e]], 1);
}

// ---------------- single-block exclusive scan (1024 thr, int4 per thread) ----------------
__global__ __launch_bounds__(1024) void scan_kernel(const int* __restrict__ cnt,
                                                    int* __restrict__ offsets, int n) {
    __shared__ int wsums[16];
    __shared__ int s_carry;
    const int tid  = threadIdx.x;
    const int lane = tid & 63;
    const int wid  = tid >> 6;
    if (tid == 0) s_carry = 0;
    __syncthreads();
    for (int base = 0; base < n; base += 4096) {
        int i0 = base + tid * 4;
        int4 v = make_int4(0, 0, 0, 0);
        if (i0 < n) v = *(const int4*)&cnt[i0];          // n % 4 == 0
        int tsum = v.x + v.y + v.z + v.w;
        int s = tsum;
        #pragma unroll
        for (int off = 1; off < 64; off <<= 1) {
            int t = __shfl_up(s, off);
            if (lane >= off) s += t;
        }
        if (lane == 63) wsums[wid] = s;
        __syncthreads();
        if (tid < 16) {
            int w = wsums[tid];
            #pragma unroll
            for (int off = 1; off < 16; off <<= 1) {
                int t = __shfl_up(w, off);
                if (tid >= off) w += t;
            }
            wsums[tid] = w;
        }
        __syncthreads();
        int wprefix = (wid > 0) ? wsums[wid - 1] : 0;
        int excl = s_carry + wprefix + (s - tsum);
        if (i0 < n) {
            int4 o;
            o.x = excl;
            o.y = o.x + v.x;
            o.z = o.y + v.y;
            o.w = o.z + v.z;
            *(int4*)&offsets[i0] = o;
        }
        __syncthreads();
        if (tid == 0) s_carry += wsums[15];
        __syncthreads();
    }
    if (tid == 0) offsets[n] = s_carry;
}

// ---------------- fill CSR buckets ----------------
__global__ void fill_kernel(const int* __restrict__ src, const int* __restrict__ dst,
                            const int* __restrict__ offsets, int* __restrict__ cursor,
                            int* __restrict__ bucket, int E) {
    int e = blockIdx.x * blockDim.x + threadIdx.x;
    if (e < E) {
        int d   = dst[e];
        int pos = atomicAdd(&cursor[d], 1);
        bucket[offsets[d] + pos] = src[e];
    }
}

// ---------------- fused: scatter-mean + dual GEMV + GELU + LN + residual ----------------
__global__ __launch_bounds__(128) void fused_kernel(
        const float* __restrict__ x,
        const float* __restrict__ WlT, const float* __restrict__ WrT,
        const float* __restrict__ bl,  const float* __restrict__ gam,
        const float* __restrict__ bet,
        const int* __restrict__ offsets, const int* __restrict__ bucket,
        float* __restrict__ out, int n_nodes) {
    __shared__ __align__(16) float vagg[D][LSTR];   // [k][n] transposed
    __shared__ __align__(16) float vx[D][LSTR];
    const int tid   = threadIdx.x;                  // 0..127 = feature index in phase A
    const int node0 = blockIdx.x * NB;

    // ---- Phase A: gather + mean, stage transposed into LDS ----
    for (int n = 0; n < NB; n++) {
        int node = node0 + n;
        float s = 0.f, xv = 0.f, inv = 0.f;
        if (node < n_nodes) {
            int o0 = offsets[node];
            int o1 = offsets[node + 1];
            int e  = o0;
            for (; e + 4 <= o1; e += 4) {
                int i0 = bucket[e], i1 = bucket[e + 1], i2 = bucket[e + 2], i3 = bucket[e + 3];
                float a0 = x[i0 * D + tid];
                float a1 = x[i1 * D + tid];
                float a2 = x[i2 * D + tid];
                float a3 = x[i3 * D + tid];
                s += (a0 + a1) + (a2 + a3);
            }
            for (; e < o1; e++) s += x[bucket[e] * D + tid];
            int deg = o1 - o0;
            inv = 1.f / (float)(deg > 0 ? deg : 1);
            xv  = x[node * D + tid];
        }
        vagg[tid][n] = s * inv;
        vx[tid][n]   = xv;
    }
    __syncthreads();

    // ---- Phase B: register-tiled dual GEMV (4 features x 4 nodes per thread) ----
    const int tj = tid & 31;    // feature group
    const int tn = tid >> 5;    // node group
    const int j0 = tj * 4;
    const int n0 = tn * 4;

    float4 blv = *(const float4*)&bl[j0];
    float acc[4][4];
    #pragma unroll
    for (int nn = 0; nn < 4; nn++) {
        acc[0][nn] = blv.x; acc[1][nn] = blv.y; acc[2][nn] = blv.z; acc[3][nn] = blv.w;
    }

    for (int k = 0; k < D; k++) {
        float4 wl = *(const float4*)&WlT[k * D + j0];
        float4 wr = *(const float4*)&WrT[k * D + j0];
        float4 va = *(const float4*)&vagg[k][n0];
        float4 vb = *(const float4*)&vx[k][n0];
        float wlv[4] = {wl.x, wl.y, wl.z, wl.w};
        float wrv[4] = {wr.x, wr.y, wr.z, wr.w};
        float vav[4] = {va.x, va.y, va.z, va.w};
        float vbv[4] = {vb.x, vb.y, vb.z, vb.w};
        #pragma unroll
        for (int jj = 0; jj < 4; jj++)
            #pragma unroll
            for (int nn = 0; nn < 4; nn++)
                acc[jj][nn] = fmaf(wlv[jj], vav[nn], fmaf(wrv[jj], vbv[nn], acc[jj][nn]));
    }

    // ---- GELU (exact erf) + LN stats ----
    float psum[4] = {0.f, 0.f, 0.f, 0.f};
    float psq[4]  = {0.f, 0.f, 0.f, 0.f};
    #pragma unroll
    for (int jj = 0; jj < 4; jj++)
        #pragma unroll
        for (int nn = 0; nn < 4; nn++) {
            float f = acc[jj][nn];
            float g = 0.5f * f * (1.f + erff(f * 0.70710678118654752440f));
            acc[jj][nn] = g;
            psum[nn] += g;
            psq[nn]  += g * g;
        }
    // reduce across the 32 feature-group lanes (tn groups are 32-lane aligned)
    #pragma unroll
    for (int m = 16; m >= 1; m >>= 1) {
        #pragma unroll
        for (int nn = 0; nn < 4; nn++) {
            psum[nn] += __shfl_xor(psum[nn], m);
            psq[nn]  += __shfl_xor(psq[nn], m);
        }
    }

    float4 gv = *(const float4*)&gam[j0];
    float4 bv = *(const float4*)&bet[j0];
    float gvv[4] = {gv.x, gv.y, gv.z, gv.w};
    float bvv[4] = {bv.x, bv.y, bv.z, bv.w};

    #pragma unroll
    for (int nn = 0; nn < 4; nn++) {
        int node = node0 + n0 + nn;
        if (node < n_nodes) {
            float mu  = psum[nn] * (1.f / (float)D);
            float var = psq[nn] * (1.f / (float)D) - mu * mu;   // biased, matches jnp.var
            float rs  = rsqrtf(var + LN_EPS);
            float4 xr = *(const float4*)&x[node * D + j0];
            float xrv[4] = {xr.x, xr.y, xr.z, xr.w};
            float o[4];
            #pragma unroll
            for (int jj = 0; jj < 4; jj++)
                o[jj] = (acc[jj][nn] - mu) * rs * gvv[jj] + bvv[jj] + xrv[jj];
            *(float4*)&out[node * D + j0] = make_float4(o[0], o[1], o[2], o[3]);
        }
    }
}

static inline size_t align_up(size_t v, size_t a) { return (v + a - 1) & ~(a - 1); }

extern "C" void kernel_launch(void* const* d_in, const int* in_sizes, int n_in,
                              void* d_out, int out_size, void* d_ws, size_t ws_size,
                              hipStream_t stream) {
    const float* x   = (const float*)d_in[0];
    const int*   ei  = (const int*)d_in[1];
    const float* Wl  = (const float*)d_in[2];
    const float* bl  = (const float*)d_in[3];
    const float* Wr  = (const float*)d_in[4];
    const float* gam = (const float*)d_in[5];
    const float* bet = (const float*)d_in[6];
    float* out = (float*)d_out;

    const int N = in_sizes[0] / D;
    const int E = in_sizes[1] / 2;
    const int* src = ei;         // edge_index row 0
    const int* dst = ei + E;     // edge_index row 1

    // workspace carve (~7.7 MB total)
    char* p = (char*)d_ws;
    int* cnt    = (int*)p;            // N
    int* cursor = cnt + N;            // N, contiguous with cnt so one memset zeroes both
    p = (char*)align_up((size_t)(cursor + N), 256);
    int* offsets = (int*)p;           // N+1
    p = (char*)align_up((size_t)(offsets + N + 1), 256);
    int* bucket = (int*)p;            // E
    p = (char*)align_up((size_t)(bucket + E), 256);
    float* WlT = (float*)p;           // D*D
    float* WrT = WlT + D * D;         // D*D

    hipMemsetAsync(cnt, 0, (size_t)2 * N * sizeof(int), stream);
    transpose_w<<<(D * D + 255) / 256, 256, 0, stream>>>(Wl, Wr, WlT, WrT);
    hist_kernel<<<(E + 255) / 256, 256, 0, stream>>>(dst, cnt, E);
    scan_kernel<<<1, 1024, 0, stream>>>(cnt, offsets, N);
    fill_kernel<<<(E + 255) / 256, 256, 0, stream>>>(src, dst, offsets, cursor, bucket, E);
    fused_kernel<<<(N + NB - 1) / NB, 128, 0, stream>>>(x, WlT, WrT, bl, gam, bet,
                                                        offsets, bucket, out, N);
}

// Round 2
// 480.017 us; speedup vs baseline: 1.1424x; 1.1424x over previous
//
#include <hip/hip_runtime.h>
#include <math.h>

#define D 128
#define NB 32            // nodes per block in fused kernel
#define LSTR 132         // LDS row stride in floats ([node][feature] layout, +4 pad)
#define LN_EPS 1e-5f
#define SCAN_CHUNK 1024

// ---------------- transpose W_l, W_r (row-major [j][k] -> [k][j]) ----------------
__global__ void transpose_w(const float* __restrict__ Wl, const float* __restrict__ Wr,
                            float* __restrict__ WlT, float* __restrict__ WrT) {
    int t = blockIdx.x * blockDim.x + threadIdx.x;   // t = k*128 + j
    if (t < D * D) {
        int j = t & (D - 1);
        int k = t >> 7;
        WlT[k * D + j] = Wl[j * D + k];
        WrT[k * D + j] = Wr[j * D + k];
    }
}

// ---------------- histogram of dst ----------------
__global__ void hist_kernel(const int* __restrict__ dst, int* __restrict__ cnt, int E) {
    int e = blockIdx.x * blockDim.x + threadIdx.x;
    if (e < E) atomicAdd(&cnt[dst[e]], 1);
}

// ---------------- scan pass 1: per-chunk sums (chunk = 1024 ints, 256 thr) ----------------
__global__ __launch_bounds__(256) void scan_partial(const int* __restrict__ cnt,
                                                    int* __restrict__ bsum, int n) {
    __shared__ int ws[4];
    const int tid = threadIdx.x;
    const int lane = tid & 63, wid = tid >> 6;
    int i0 = blockIdx.x * SCAN_CHUNK + tid * 4;
    int4 v = make_int4(0, 0, 0, 0);
    if (i0 < n) v = *(const int4*)&cnt[i0];        // n % 4 == 0
    int t = v.x + v.y + v.z + v.w;
    #pragma unroll
    for (int m = 32; m >= 1; m >>= 1) t += __shfl_xor(t, m);
    if (lane == 0) ws[wid] = t;
    __syncthreads();
    if (tid == 0) bsum[blockIdx.x] = ws[0] + ws[1] + ws[2] + ws[3];
}

// ---------------- scan pass 2: exclusive scan of chunk sums (1 block, 1024 thr) ----------------
__global__ __launch_bounds__(1024) void scan_base(const int* __restrict__ bsum,
                                                  int* __restrict__ bbase,
                                                  int* __restrict__ offsets,
                                                  int nb, int n) {
    __shared__ int wsums[16];
    const int tid = threadIdx.x;
    const int lane = tid & 63, wid = tid >> 6;
    int v = (tid < nb) ? bsum[tid] : 0;
    int s = v;
    #pragma unroll
    for (int off = 1; off < 64; off <<= 1) {
        int t = __shfl_up(s, off);
        if (lane >= off) s += t;
    }
    if (lane == 63) wsums[wid] = s;
    __syncthreads();
    if (tid < 16) {
        int w = wsums[tid];
        #pragma unroll
        for (int off = 1; off < 16; off <<= 1) {
            int t = __shfl_up(w, off);
            if (tid >= off) w += t;
        }
        wsums[tid] = w;
    }
    __syncthreads();
    int wprefix = (wid > 0) ? wsums[wid - 1] : 0;
    if (tid < nb) bbase[tid] = wprefix + (s - v);   // exclusive
    if (tid == 0) offsets[n] = wsums[15];           // grand total
}

// ---------------- scan pass 3: per-chunk exclusive scan + base ----------------
__global__ __launch_bounds__(256) void scan_final(const int* __restrict__ cnt,
                                                  const int* __restrict__ bbase,
                                                  int* __restrict__ offsets, int n) {
    __shared__ int ws[4];
    __shared__ int wpre[4];
    const int tid = threadIdx.x;
    const int lane = tid & 63, wid = tid >> 6;
    int i0 = blockIdx.x * SCAN_CHUNK + tid * 4;
    int4 v = make_int4(0, 0, 0, 0);
    if (i0 < n) v = *(const int4*)&cnt[i0];
    int tsum = v.x + v.y + v.z + v.w;
    int s = tsum;
    #pragma unroll
    for (int off = 1; off < 64; off <<= 1) {
        int t = __shfl_up(s, off);
        if (lane >= off) s += t;
    }
    if (lane == 63) ws[wid] = s;
    __syncthreads();
    if (tid == 0) {
        int a = 0;
        #pragma unroll
        for (int i = 0; i < 4; i++) { wpre[i] = a; a += ws[i]; }
    }
    __syncthreads();
    if (i0 < n) {
        int excl = bbase[blockIdx.x] + wpre[wid] + (s - tsum);
        int4 o;
        o.x = excl;
        o.y = o.x + v.x;
        o.z = o.y + v.y;
        o.w = o.z + v.z;
        *(int4*)&offsets[i0] = o;
    }
}

// ---------------- fill CSR buckets ----------------
__global__ void fill_kernel(const int* __restrict__ src, const int* __restrict__ dst,
                            const int* __restrict__ offsets, int* __restrict__ cursor,
                            int* __restrict__ bucket, int E) {
    int e = blockIdx.x * blockDim.x + threadIdx.x;
    if (e < E) {
        int d   = dst[e];
        int pos = atomicAdd(&cursor[d], 1);
        bucket[offsets[d] + pos] = src[e];
    }
}

// ---------------- fused: scatter-mean + dual GEMV + GELU + LN + residual ----------------
__global__ __launch_bounds__(256, 4) void fused_kernel(
        const float* __restrict__ x,
        const float* __restrict__ WlT, const float* __restrict__ WrT,
        const float* __restrict__ bl,  const float* __restrict__ gam,
        const float* __restrict__ bet,
        const int* __restrict__ offsets, const int* __restrict__ bucket,
        float* __restrict__ out, int n_nodes) {
    __shared__ __align__(16) float sagg[NB * LSTR];   // [node][feature], mean-aggregated
    __shared__ __align__(16) float sx[NB * LSTR];     // [node][feature], own features
    const int tid   = threadIdx.x;
    const int node0 = blockIdx.x * NB;

    // ---- Phase A: half-wave (32 lanes x float4) per node; edge loop unrolled x4 ----
    const int hl  = tid & 31;        // lane within half-wave
    const int hw  = tid >> 5;        // half-wave id, 0..7
    const int hl4 = hl * 4;
    #pragma unroll
    for (int r = 0; r < NB / 8; r++) {
        const int n = r * 8 + hw;
        const int g = node0 + n;
        float sx_ = 0.f, sy_ = 0.f, sz_ = 0.f, sw_ = 0.f;
        float4 xv = make_float4(0.f, 0.f, 0.f, 0.f);
        float inv = 0.f;
        if (g < n_nodes) {
            const int o0 = offsets[g];
            const int o1 = offsets[g + 1];
            int e = o0;
            for (; e + 4 <= o1; e += 4) {
                int i0 = bucket[e], i1 = bucket[e + 1], i2 = bucket[e + 2], i3 = bucket[e + 3];
                float4 a0 = *(const float4*)&x[i0 * D + hl4];
                float4 a1 = *(const float4*)&x[i1 * D + hl4];
                float4 a2 = *(const float4*)&x[i2 * D + hl4];
                float4 a3 = *(const float4*)&x[i3 * D + hl4];
                sx_ += (a0.x + a1.x) + (a2.x + a3.x);
                sy_ += (a0.y + a1.y) + (a2.y + a3.y);
                sz_ += (a0.z + a1.z) + (a2.z + a3.z);
                sw_ += (a0.w + a1.w) + (a2.w + a3.w);
            }
            for (; e < o1; e++) {
                float4 a = *(const float4*)&x[bucket[e] * D + hl4];
                sx_ += a.x; sy_ += a.y; sz_ += a.z; sw_ += a.w;
            }
            int deg = o1 - o0;
            inv = 1.f / (float)(deg > 0 ? deg : 1);
            xv = *(const float4*)&x[g * D + hl4];
        }
        *(float4*)&sagg[n * LSTR + hl4] = make_float4(sx_ * inv, sy_ * inv, sz_ * inv, sw_ * inv);
        *(float4*)&sx[n * LSTR + hl4]   = xv;
    }
    __syncthreads();

    // ---- Phase B: dual GEMV, thread = 4 features x 4 nodes, k-chunked by 4 ----
    const int tj = tid & 31;     // feature group
    const int tn = tid >> 5;     // node group, 0..7
    const int j0 = tj * 4;
    const int n0 = tn * 4;

    float4 blv = *(const float4*)&bl[j0];
    float acc[4][4];
    #pragma unroll
    for (int nn = 0; nn < 4; nn++) {
        acc[0][nn] = blv.x; acc[1][nn] = blv.y; acc[2][nn] = blv.z; acc[3][nn] = blv.w;
    }

    for (int kc = 0; kc < D; kc += 4) {
        float4 av[4], bv[4];
        #pragma unroll
        for (int nn = 0; nn < 4; nn++) {
            av[nn] = *(const float4*)&sagg[(n0 + nn) * LSTR + kc];
            bv[nn] = *(const float4*)&sx[(n0 + nn) * LSTR + kc];
        }
        #pragma unroll
        for (int kk = 0; kk < 4; kk++) {
            float4 wl = *(const float4*)&WlT[(kc + kk) * D + j0];
            float4 wr = *(const float4*)&WrT[(kc + kk) * D + j0];
            float wlv[4] = {wl.x, wl.y, wl.z, wl.w};
            float wrv[4] = {wr.x, wr.y, wr.z, wr.w};
            #pragma unroll
            for (int nn = 0; nn < 4; nn++) {
                float a = ((const float*)&av[nn])[kk];
                float b = ((const float*)&bv[nn])[kk];
                #pragma unroll
                for (int jj = 0; jj < 4; jj++)
                    acc[jj][nn] = fmaf(wlv[jj], a, fmaf(wrv[jj], b, acc[jj][nn]));
            }
        }
    }

    // ---- GELU (exact erf) + LN stats ----
    float psum[4] = {0.f, 0.f, 0.f, 0.f};
    float psq[4]  = {0.f, 0.f, 0.f, 0.f};
    #pragma unroll
    for (int jj = 0; jj < 4; jj++)
        #pragma unroll
        for (int nn = 0; nn < 4; nn++) {
            float f = acc[jj][nn];
            float g = 0.5f * f * (1.f + erff(f * 0.70710678118654752440f));
            acc[jj][nn] = g;
            psum[nn] += g;
            psq[nn]  += g * g;
        }
    // reduce across the 32 feature-group lanes (node groups are 32-lane aligned)
    #pragma unroll
    for (int m = 16; m >= 1; m >>= 1) {
        #pragma unroll
        for (int nn = 0; nn < 4; nn++) {
            psum[nn] += __shfl_xor(psum[nn], m);
            psq[nn]  += __shfl_xor(psq[nn], m);
        }
    }

    float4 gv = *(const float4*)&gam[j0];
    float4 bvv4 = *(const float4*)&bet[j0];
    float gvv[4] = {gv.x, gv.y, gv.z, gv.w};
    float bvv[4] = {bvv4.x, bvv4.y, bvv4.z, bvv4.w};

    #pragma unroll
    for (int nn = 0; nn < 4; nn++) {
        int node = node0 + n0 + nn;
        if (node < n_nodes) {
            float mu  = psum[nn] * (1.f / (float)D);
            float var = psq[nn] * (1.f / (float)D) - mu * mu;   // biased, matches jnp.var
            float rs  = rsqrtf(var + LN_EPS);
            float4 xr = *(const float4*)&x[node * D + j0];
            float xrv[4] = {xr.x, xr.y, xr.z, xr.w};
            float o[4];
            #pragma unroll
            for (int jj = 0; jj < 4; jj++)
                o[jj] = (acc[jj][nn] - mu) * rs * gvv[jj] + bvv[jj] + xrv[jj];
            *(float4*)&out[node * D + j0] = make_float4(o[0], o[1], o[2], o[3]);
        }
    }
}

static inline size_t align_up(size_t v, size_t a) { return (v + a - 1) & ~(a - 1); }

extern "C" void kernel_launch(void* const* d_in, const int* in_sizes, int n_in,
                              void* d_out, int out_size, void* d_ws, size_t ws_size,
                              hipStream_t stream) {
    const float* x   = (const float*)d_in[0];
    const int*   ei  = (const int*)d_in[1];
    const float* Wl  = (const float*)d_in[2];
    const float* bl  = (const float*)d_in[3];
    const float* Wr  = (const float*)d_in[4];
    const float* gam = (const float*)d_in[5];
    const float* bet = (const float*)d_in[6];
    float* out = (float*)d_out;

    const int N = in_sizes[0] / D;
    const int E = in_sizes[1] / 2;
    const int* src = ei;         // edge_index row 0
    const int* dst = ei + E;     // edge_index row 1
    const int nblk = (N + SCAN_CHUNK - 1) / SCAN_CHUNK;   // 98 for N=100000

    // workspace carve (~7.7 MB total)
    char* p = (char*)d_ws;
    int* cnt    = (int*)p;            // N
    int* cursor = cnt + N;            // N, contiguous with cnt so one memset zeroes both
    p = (char*)align_up((size_t)(cursor + N), 256);
    int* offsets = (int*)p;           // N+1
    p = (char*)align_up((size_t)(offsets + N + 1), 256);
    int* bucket = (int*)p;            // E
    p = (char*)align_up((size_t)(bucket + E), 256);
    float* WlT = (float*)p;           // D*D
    float* WrT = WlT + D * D;         // D*D
    p = (char*)align_up((size_t)(WrT + D * D), 256);
    int* bsum  = (int*)p;             // nblk
    int* bbase = bsum + 1024;         // nblk

    hipMemsetAsync(cnt, 0, (size_t)2 * N * sizeof(int), stream);
    transpose_w<<<(D * D + 255) / 256, 256, 0, stream>>>(Wl, Wr, WlT, WrT);
    hist_kernel<<<(E + 255) / 256, 256, 0, stream>>>(dst, cnt, E);
    scan_partial<<<nblk, 256, 0, stream>>>(cnt, bsum, N);
    scan_base<<<1, 1024, 0, stream>>>(bsum, bbase, offsets, nblk, N);
    scan_final<<<nblk, 256, 0, stream>>>(cnt, bbase, offsets, N);
    fill_kernel<<<(E + 255) / 256, 256, 0, stream>>>(src, dst, offsets, cursor, bucket, E);
    fused_kernel<<<(N + NB - 1) / NB, 256, 0, stream>>>(x, WlT, WrT, bl, gam, bet,
                                                        offsets, bucket, out, N);
}